// Round 2
// baseline (173.535 us; speedup 1.0000x reference)
//
#include <hip/hip_runtime.h>

// Grid (voxel) mean pooling. x in [0,1)^3, voxel=floor(x*20) -> <=8000 bins.
// Raw hash (vx*20+vy)*20+vz is monotone-lexicographic like the reference's
// shifted hash -> identical grouping AND identical sorted-unique order.
//
// R11: R10's fused persistent kernel, hang-hardened.
//  - BUG FIX: R10 had 64B static __shared__ (wsum) ON TOP of 65536B dynamic
//    -> 65600B > the 65536B attribute -> invalid launch inside graph
//    capture -> container death. wsum now lives inside the dynamic region.
//  - Barrier simplified: two one-shot counters (no reset/generation),
//    re-zeroed each launch by init_kernel (ws is re-poisoned per iter).
//  - Spin is BOUNDED: a broken barrier now yields a finite wrong-answer
//    run (diagnosable) instead of a watchdog kill.
// Co-residency is guaranteed by capacity: 256 blocks <= 1 block/CU * 256
// CUs (64KB LDS caps 2/CU; 1024 thr caps 2/CU; either way capacity >= 256).
// Accum phase unchanged (R9): 1 u64 LDS atomic/point,
// [qx:19|qy:19|qz:19|cnt:7] at 2^12 fixed point.

#define NBINS 8000
#define NBINS_PAD 8192
#define ACC_BLOCKS 256
#define ACC_THREADS 1024
typedef unsigned long long u64;

// agent-scope atomic load: reads through to the coherence point, never a
// stale per-XCD L2 line (a plain/volatile load could spin forever).
__device__ __forceinline__ unsigned gload(unsigned* p) {
    return __hip_atomic_load(p, __ATOMIC_RELAXED, __HIP_MEMORY_SCOPE_AGENT);
}

// one-shot grid barrier on a dedicated counter cell. Bounded spin: if the
// barrier is broken we produce wrong results in finite time, not a hang.
__device__ __forceinline__ void grid_barrier(unsigned* cell) {
    __syncthreads();
    if (threadIdx.x == 0) {
        __threadfence();                   // release: L2 writeback (agent scope)
        atomicAdd(cell, 1u);
        unsigned spins = 0;
        while (gload(cell) < ACC_BLOCKS && spins < (1u << 20)) {
            __builtin_amdgcn_s_sleep(8);
            ++spins;
        }
        __threadfence();                   // acquire: invalidate stale caches
    }
    __syncthreads();
}

__global__ void init_kernel(unsigned* bar) {
    // atomics so the zeros land at the coherence point before fused starts
    atomicExch(&bar[0], 0u);
    atomicExch(&bar[1], 0u);
}

__global__ __launch_bounds__(ACC_THREADS)
void fused_kernel(const float* __restrict__ x, int N,
                  u64* __restrict__ partials, float* __restrict__ bins,
                  float* __restrict__ out, int out_size,
                  unsigned* __restrict__ bar) {
    extern __shared__ u64 lds[];               // [8192] packed bins, 64 KB
    const float scale = 20.0f;                 // 1.0/0.05 is exactly 20.0f
    const float FP = 4096.0f;                  // 2^12 fixed-point scale
    const int t = threadIdx.x;
    const int bid = blockIdx.x;

    // ---------------- phase A: LDS-atomic accumulate + flush ----------------
    float4* lds4 = (float4*)lds;
    #pragma unroll
    for (int k = 0; k < 4; ++k)                // 8192*8B / 16B / 1024thr = 4
        lds4[t + k * ACC_THREADS] = make_float4(0.f, 0.f, 0.f, 0.f);
    __syncthreads();

    const float4* xv = (const float4*)x;
    long long nquads = ((long long)N + 3) / 4;
    long long gstride = (long long)ACC_BLOCKS * ACC_THREADS;
    for (long long q = (long long)bid * ACC_THREADS + t; q < nquads;
         q += gstride) {
        float px[4], py[4], pz[4];
        int npts;
        if (q * 4 + 4 <= N) {
            float4 a = xv[3 * q + 0];
            float4 b = xv[3 * q + 1];
            float4 c = xv[3 * q + 2];
            px[0] = a.x; py[0] = a.y; pz[0] = a.z;
            px[1] = a.w; py[1] = b.x; pz[1] = b.y;
            px[2] = b.z; py[2] = b.w; pz[2] = c.x;
            px[3] = c.y; py[3] = c.z; pz[3] = c.w;
            npts = 4;
        } else {
            npts = (int)(N - q * 4);
            for (int j = 0; j < npts; ++j) {
                px[j] = x[3 * (q * 4 + j) + 0];
                py[j] = x[3 * (q * 4 + j) + 1];
                pz[j] = x[3 * (q * 4 + j) + 2];
            }
        }
        #pragma unroll
        for (int j = 0; j < 4; ++j) {
            if (j >= npts) break;
            int vx = (int)floorf(px[j] * scale);
            int vy = (int)floorf(py[j] * scale);
            int vz = (int)floorf(pz[j] * scale);
            vx = min(max(vx, 0), 19);          // safety; no-op for x in [0,1)
            vy = min(max(vy, 0), 19);
            vz = min(max(vz, 0), 19);
            int h = (vx * 20 + vy) * 20 + vz;
            u64 qx = (u64)(unsigned)(px[j] * FP + 0.5f);   // <= 4096 < 2^13
            u64 qy = (u64)(unsigned)(py[j] * FP + 0.5f);
            u64 qz = (u64)(unsigned)(pz[j] * FP + 0.5f);
            atomicAdd(&lds[h], (qx << 45) | (qy << 26) | (qz << 7) | 1ull);
        }
    }
    __syncthreads();

    float4* p4 = (float4*)(partials + (size_t)bid * NBINS_PAD);
    #pragma unroll
    for (int k = 0; k < 4; ++k)
        p4[t + k * ACC_THREADS] = lds4[t + k * ACC_THREADS];

    grid_barrier(&bar[0]);

    // ------- phase B: 256-slice reduce -> bins SoA; plus out zeroing -------
    // thread (sg = t>>5, bo = t&31) sums slices sg*8..sg*8+7 of bin
    // bid*32+bo.  Integer adds are associative -> exact same sums as the
    // old reduce1+reduce2 chain.  u32 safe: 8 * 2^19 < 2^22.
    {
        const int sg = t >> 5;
        const int bo = t & 31;
        const int bin = bid * 32 + bo;
        unsigned sx = 0, sy = 0, sz = 0, c = 0;
        #pragma unroll
        for (int k = 0; k < 8; ++k) {
            u64 v = partials[(size_t)(sg * 8 + k) * NBINS_PAD + bin];
            c  += (unsigned)(v & 127u);
            sz += (unsigned)((v >> 7)  & 0x7FFFFu);
            sy += (unsigned)((v >> 26) & 0x7FFFFu);
            sx += (unsigned)(v >> 45);
        }
        // lanes l and l^32 hold adjacent slice-groups of the same bin
        sx += __shfl_xor(sx, 32, 64);
        sy += __shfl_xor(sy, 32, 64);
        sz += __shfl_xor(sz, 32, 64);
        c  += __shfl_xor(c, 32, 64);
        uint4* lw = (uint4*)lds;               // reuse LDS (8 KB of it)
        if ((t & 63) < 32) lw[(t >> 6) * 32 + bo] = make_uint4(sx, sy, sz, c);
        __syncthreads();
        if (t < 32) {                          // final 16-wave sum, u64 acc
            u64 fx = 0, fy = 0, fz = 0, fc = 0;
            #pragma unroll
            for (int w2 = 0; w2 < 16; ++w2) {
                uint4 v = lw[w2 * 32 + t];
                fx += v.x; fy += v.y; fz += v.z; fc += v.w;
            }
            const float inv = 1.0f / 4096.0f;
            int b2 = bid * 32 + t;
            bins[0 * NBINS_PAD + b2] = (float)fx * inv;
            bins[1 * NBINS_PAD + b2] = (float)fy * inv;
            bins[2 * NBINS_PAD + b2] = (float)fz * inv;
            bins[3 * NBINS_PAD + b2] = (float)fc;
        }
    }
    // zero out floats [24000, total4*4) -- can never be touched by phase C
    // (C writes [0,3K) and zeros [3K,24000), K<=8000). Overlaps the reduce.
    {
        const float4 zero4 = make_float4(0.f, 0.f, 0.f, 0.f);
        float4* out4 = (float4*)out;
        long long total4 = out_size >> 2;
        for (long long oi = (long long)(NBINS * 3 / 4) + bid * ACC_THREADS + t;
             oi < total4; oi += (long long)ACC_BLOCKS * ACC_THREADS)
            out4[oi] = zero4;
    }

    grid_barrier(&bar[1]);

    // ---------------- phase C: block 0 scan + compaction --------------------
    if (bid != 0) return;
    {
        int* wsum = (int*)lds;                 // reuse dynamic LDS (64 B)
        int lane = t & 63;
        int w = t >> 6;                        // 16 waves
        int base = t * 8;

        float c[8];
        int occ[8];
        int tot = 0;
        #pragma unroll
        for (int j = 0; j < 8; ++j) {
            int b = base + j;
            c[j] = (b < NBINS) ? bins[3 * NBINS_PAD + b] : 0.0f;
            occ[j] = (c[j] > 0.0f) ? 1 : 0;
            tot += occ[j];
        }

        int v = tot;                           // inclusive wave scan
        #pragma unroll
        for (int d = 1; d < 64; d <<= 1) {
            int o = __shfl_up(v, d, 64);
            if (lane >= d) v += o;
        }
        if (lane == 63) wsum[w] = v;
        __syncthreads();
        if (w == 0 && lane < 16) {             // scan the 16 wave sums
            int s = wsum[lane];
            #pragma unroll
            for (int d = 1; d < 16; d <<= 1) {
                int o = __shfl_up(s, d, 64);
                if (lane >= d) s += o;
            }
            wsum[lane] = s;
        }
        __syncthreads();
        int r = (w ? wsum[w - 1] : 0) + v - tot;   // exclusive prefix

        #pragma unroll
        for (int j = 0; j < 8; ++j) {
            if (occ[j]) {
                int b = base + j;
                float icnt = 1.0f / c[j];
                out[3 * r + 0] = bins[0 * NBINS_PAD + b] * icnt;
                out[3 * r + 1] = bins[1 * NBINS_PAD + b] * icnt;
                out[3 * r + 2] = bins[2 * NBINS_PAD + b] * icnt;
                ++r;
            }
        }

        // zero [3K, 24000): rows K..NBINS must be zero if K < NBINS
        int K = wsum[15];
        int zend = min(NBINS * 3, out_size);
        for (int e = 3 * K + t; e < zend; e += ACC_THREADS) out[e] = 0.f;

        // scalar tail not covered by the float4 zeroing (if out_size % 4)
        if (t == 0) {
            long long total4 = out_size >> 2;
            for (long long e = total4 * 4; e < out_size; ++e) out[e] = 0.f;
        }
    }
}

extern "C" void kernel_launch(void* const* d_in, const int* in_sizes, int n_in,
                              void* d_out, int out_size, void* d_ws, size_t ws_size,
                              hipStream_t stream) {
    const float* x = (const float*)d_in[0];
    int N = in_sizes[0] / 3;
    float* out = (float*)d_out;

    // ws layout: partials [256 * 64KB = 16MB] | bins [4*8192 f32 = 128KB]
    //            | barrier cells [2 u32]
    u64* partials = (u64*)d_ws;
    float* bins = (float*)(partials + (size_t)ACC_BLOCKS * NBINS_PAD);
    unsigned* bar = (unsigned*)(bins + 4 * NBINS_PAD);

    hipFuncSetAttribute(reinterpret_cast<const void*>(&fused_kernel),
                        hipFuncAttributeMaxDynamicSharedMemorySize, 65536);

    init_kernel<<<1, 1, 0, stream>>>(bar);
    fused_kernel<<<ACC_BLOCKS, ACC_THREADS, NBINS_PAD * sizeof(u64), stream>>>(
        x, N, partials, bins, out, out_size, bar);
}

// Round 3
// 118.421 us; speedup vs baseline: 1.4654x; 1.4654x over previous
//
#include <hip/hip_runtime.h>

// Grid (voxel) mean pooling. x in [0,1)^3, voxel=floor(x*20) -> <=8000 bins.
// Raw hash (vx*20+vy)*20+vz is monotone-lexicographic like the reference's
// shifted hash -> identical grouping AND identical sorted-unique order.
//
// R12: fence-free fused kernel. R11 measured 103.5us vs ~53us sum-of-parts;
// low VALU (4%) / low BW (12%) / low bank-conflict rules out compute+memory.
// Suspect: __threadfence() in each grid barrier = buffer_wbl2 + buffer_inv
// (full L2 walk/writeback) x 256 blocks x 2 barriers, plus barrier-2's
// release forcing synchronous writeback of the 48MB zero-fill.
// Fixes:
//  - Cross-block data (partials, cnt) via agent-scope RELAXED atomic
//    stores/loads -> coherent at IC with NO cache-maintenance instructions.
//    Barrier = vmcnt drain + syncthreads + atomicAdd + bounded spin. No
//    threadfence anywhere.
//  - Phase C fully distributed: per-block bin sums stay in REGISTERS across
//    barrier 2; only a 4B occupied-count is published. Every block scans
//    the 256 counts and writes its own <=32 rows. 'bins' array deleted.
//  - 48MB output zeroing issued between barrier-2 arrival and wait
//    (overlaps the spin); plain stores (host-only data needs no fence).
// Numerics bit-identical to R9/R11 (same integer sum order, same float
// conversion chain).

#define NBINS 8000
#define NBINS_PAD 8192
#define ACC_BLOCKS 256
#define ACC_THREADS 1024
typedef unsigned long long u64;

__device__ __forceinline__ unsigned gload(const unsigned* p) {
    return __hip_atomic_load(p, __ATOMIC_RELAXED, __HIP_MEMORY_SCOPE_AGENT);
}
__device__ __forceinline__ void sc_store64(u64* p, u64 v) {
    __hip_atomic_store(p, v, __ATOMIC_RELAXED, __HIP_MEMORY_SCOPE_AGENT);
}
__device__ __forceinline__ u64 sc_load64(const u64* p) {
    return __hip_atomic_load(p, __ATOMIC_RELAXED, __HIP_MEMORY_SCOPE_AGENT);
}
__device__ __forceinline__ void sc_store32(unsigned* p, unsigned v) {
    __hip_atomic_store(p, v, __ATOMIC_RELAXED, __HIP_MEMORY_SCOPE_AGENT);
}

// fence-free one-shot grid barrier. Prior sc-stores are already at the
// coherence point; vmcnt(0) + syncthreads orders them before arrival.
// Bounded spin: a broken barrier gives a finite wrong-answer, not a hang.
__device__ __forceinline__ void arrive_and_wait(unsigned* cell) {
    asm volatile("s_waitcnt vmcnt(0)" ::: "memory");
    __syncthreads();
    if (threadIdx.x == 0) {
        atomicAdd(cell, 1u);
        unsigned spins = 0;
        while (gload(cell) < ACC_BLOCKS && spins < (1u << 20)) {
            __builtin_amdgcn_s_sleep(8);
            ++spins;
        }
    }
    __syncthreads();
}

__global__ void init_kernel(unsigned* bar) {
    atomicExch(&bar[0], 0u);
    atomicExch(&bar[1], 0u);
}

__global__ __launch_bounds__(ACC_THREADS)
void fused_kernel(const float* __restrict__ x, int N,
                  u64* __restrict__ partials, unsigned* __restrict__ cnt,
                  float* __restrict__ out, int out_size,
                  unsigned* __restrict__ bar) {
    extern __shared__ u64 lds[];               // [8192] packed bins, 64 KB
    const float scale = 20.0f;                 // 1.0/0.05 is exactly 20.0f
    const float FP = 4096.0f;                  // 2^12 fixed-point scale
    const int t = threadIdx.x;
    const int bid = blockIdx.x;

    // ---------------- phase A: LDS-atomic accumulate ----------------
    float4* lds4 = (float4*)lds;
    #pragma unroll
    for (int k = 0; k < 4; ++k)                // 8192*8B / 16B / 1024thr = 4
        lds4[t + k * ACC_THREADS] = make_float4(0.f, 0.f, 0.f, 0.f);
    __syncthreads();

    const float4* xv = (const float4*)x;
    long long nquads = ((long long)N + 3) / 4;
    long long gstride = (long long)ACC_BLOCKS * ACC_THREADS;
    for (long long q = (long long)bid * ACC_THREADS + t; q < nquads;
         q += gstride) {
        float px[4], py[4], pz[4];
        int npts;
        if (q * 4 + 4 <= N) {
            float4 a = xv[3 * q + 0];
            float4 b = xv[3 * q + 1];
            float4 c = xv[3 * q + 2];
            px[0] = a.x; py[0] = a.y; pz[0] = a.z;
            px[1] = a.w; py[1] = b.x; pz[1] = b.y;
            px[2] = b.z; py[2] = b.w; pz[2] = c.x;
            px[3] = c.y; py[3] = c.z; pz[3] = c.w;
            npts = 4;
        } else {
            npts = (int)(N - q * 4);
            for (int j = 0; j < npts; ++j) {
                px[j] = x[3 * (q * 4 + j) + 0];
                py[j] = x[3 * (q * 4 + j) + 1];
                pz[j] = x[3 * (q * 4 + j) + 2];
            }
        }
        #pragma unroll
        for (int j = 0; j < 4; ++j) {
            if (j >= npts) break;
            int vx = (int)floorf(px[j] * scale);
            int vy = (int)floorf(py[j] * scale);
            int vz = (int)floorf(pz[j] * scale);
            vx = min(max(vx, 0), 19);          // safety; no-op for x in [0,1)
            vy = min(max(vy, 0), 19);
            vz = min(max(vz, 0), 19);
            int h = (vx * 20 + vy) * 20 + vz;
            u64 qx = (u64)(unsigned)(px[j] * FP + 0.5f);   // <= 4096 < 2^13
            u64 qy = (u64)(unsigned)(py[j] * FP + 0.5f);
            u64 qz = (u64)(unsigned)(pz[j] * FP + 0.5f);
            atomicAdd(&lds[h], (qx << 45) | (qy << 26) | (qz << 7) | 1ull);
        }
    }
    __syncthreads();

    // flush slice via agent-scope stores (land at IC -> no fence needed)
    #pragma unroll
    for (int k = 0; k < 8; ++k) {
        int idx = t + k * ACC_THREADS;
        sc_store64(&partials[(size_t)bid * NBINS_PAD + idx], lds[idx]);
    }

    arrive_and_wait(&bar[0]);

    // ------- phase B: 256-slice reduce -> per-block register bins -------
    // thread (sg = t>>5, bo = t&31) sums slices sg*8..sg*8+7 of bin
    // bid*32+bo. Same integer sum order as R9/R11 -> bit-identical.
    const int sg = t >> 5;
    const int bo = t & 31;
    const int bin = bid * 32 + bo;
    unsigned sx = 0, sy = 0, sz = 0, c = 0;
    #pragma unroll
    for (int k = 0; k < 8; ++k) {
        u64 v = sc_load64(&partials[(size_t)(sg * 8 + k) * NBINS_PAD + bin]);
        c  += (unsigned)(v & 127u);
        sz += (unsigned)((v >> 7)  & 0x7FFFFu);
        sy += (unsigned)((v >> 26) & 0x7FFFFu);
        sx += (unsigned)(v >> 45);
    }
    sx += __shfl_xor(sx, 32, 64);              // lane l ^ 32 = adjacent sg
    sy += __shfl_xor(sy, 32, 64);
    sz += __shfl_xor(sz, 32, 64);
    c  += __shfl_xor(c, 32, 64);
    uint4* lw = (uint4*)lds;                   // reuse LDS (8 KB)
    if ((t & 63) < 32) lw[(t >> 6) * 32 + bo] = make_uint4(sx, sy, sz, c);
    __syncthreads();

    u64 fx = 0, fy = 0, fz = 0, fc = 0;        // this block's bin t (t<32)
    if (t < 32) {
        #pragma unroll
        for (int w2 = 0; w2 < 16; ++w2) {
            uint4 v = lw[w2 * 32 + t];
            fx += v.x; fy += v.y; fz += v.z; fc += v.w;
        }
        u64 bal = __ballot(fc != 0);           // lanes 32+ inactive -> 0
        if (t == 0) sc_store32(&cnt[bid], (unsigned)__popcll(bal));
    }

    // barrier 2: arrive, then overlap the 48MB zeroing with the spin.
    if (t == 0) {
        asm volatile("s_waitcnt vmcnt(0)" ::: "memory");  // drain cnt store
        atomicAdd(&bar[1], 1u);
    }
    {
        // zero out floats [24000, total4*4): never touched by phase C
        const float4 zero4 = make_float4(0.f, 0.f, 0.f, 0.f);
        float4* out4 = (float4*)out;
        long long total4 = out_size >> 2;
        for (long long oi = (long long)(NBINS * 3 / 4) + bid * ACC_THREADS + t;
             oi < total4; oi += (long long)ACC_BLOCKS * ACC_THREADS)
            out4[oi] = zero4;
    }
    if (t == 0) {
        unsigned spins = 0;
        while (gload(&bar[1]) < ACC_BLOCKS && spins < (1u << 20)) {
            __builtin_amdgcn_s_sleep(8);
            ++spins;
        }
    }
    __syncthreads();

    // ------- phase C (distributed): rank from global cnt scan, write rows --
    unsigned* ldsu = (unsigned*)lds;
    if (t < 64) {                              // wave 0: scan 256 counts
        unsigned c4[4];
        unsigned s = 0;
        #pragma unroll
        for (int i = 0; i < 4; ++i) {
            c4[i] = gload(&cnt[4 * t + i]);
            s += c4[i];
        }
        unsigned v = s;                        // inclusive scan over 64 lanes
        #pragma unroll
        for (int d = 1; d < 64; d <<= 1) {
            unsigned o = __shfl_up(v, d, 64);
            if (t >= d) v += o;
        }
        unsigned excl = v - s;
        ldsu[4 * t + 0] = excl;
        ldsu[4 * t + 1] = excl + c4[0];
        ldsu[4 * t + 2] = excl + c4[0] + c4[1];
        ldsu[4 * t + 3] = excl + c4[0] + c4[1] + c4[2];
        if (t == 63) ldsu[256] = v;            // K = total occupied
    }
    __syncthreads();
    const unsigned base_b = ldsu[bid];
    const unsigned K = ldsu[256];

    if (t < 32) {
        int occ = (fc != 0) ? 1 : 0;
        int v = occ;                           // rank within block's 32 bins
        #pragma unroll
        for (int d = 1; d < 32; d <<= 1) {
            int o = __shfl_up(v, d, 64);
            if (t >= d) v += o;
        }
        if (occ) {
            int r = (int)base_b + v - 1;
            const float inv = 1.0f / 4096.0f;  // same op chain as R9/R11
            float icnt = 1.0f / (float)fc;
            out[3 * r + 0] = ((float)fx * inv) * icnt;
            out[3 * r + 1] = ((float)fy * inv) * icnt;
            out[3 * r + 2] = ((float)fz * inv) * icnt;
        }
    }
    // zero rows [K, NBINS): floats [3K, min(3*NBINS, out_size))
    {
        int zend = min(NBINS * 3, out_size);
        for (int e = 3 * (int)K + bid * ACC_THREADS + t; e < zend;
             e += ACC_BLOCKS * ACC_THREADS)
            out[e] = 0.f;
    }
    // scalar tail if out_size % 4 (not covered by float4 zeroing)
    if (bid == 0 && t == 0) {
        long long total4 = out_size >> 2;
        for (long long e = total4 * 4; e < out_size; ++e) out[e] = 0.f;
    }
}

extern "C" void kernel_launch(void* const* d_in, const int* in_sizes, int n_in,
                              void* d_out, int out_size, void* d_ws, size_t ws_size,
                              hipStream_t stream) {
    const float* x = (const float*)d_in[0];
    int N = in_sizes[0] / 3;
    float* out = (float*)d_out;

    // ws layout: partials [256*64KB = 16MB] | cnt [256 u32] | bar [2 u32]
    u64* partials = (u64*)d_ws;
    unsigned* cnt = (unsigned*)(partials + (size_t)ACC_BLOCKS * NBINS_PAD);
    unsigned* bar = cnt + ACC_BLOCKS;

    hipFuncSetAttribute(reinterpret_cast<const void*>(&fused_kernel),
                        hipFuncAttributeMaxDynamicSharedMemorySize, 65536);

    init_kernel<<<1, 1, 0, stream>>>(bar);
    fused_kernel<<<ACC_BLOCKS, ACC_THREADS, NBINS_PAD * sizeof(u64), stream>>>(
        x, N, partials, cnt, out, out_size, bar);
}